// Round 3
// baseline (301.420 us; speedup 1.0000x reference)
//
#include <hip/hip_runtime.h>
#include <stdint.h>

typedef __attribute__((ext_vector_type(4))) float f32x4;
typedef __attribute__((ext_vector_type(8))) short s16x8;

__device__ __forceinline__ unsigned int f2bf_u(float x) {
  union { float f; unsigned int u; } v; v.f = x;
  return (v.u + 0x7FFFu + ((v.u >> 16) & 1u)) >> 16;   // RNE
}
__device__ __forceinline__ unsigned int pack_bf2(float lo, float hi) {
  return f2bf_u(lo) | (f2bf_u(hi) << 16);
}
__device__ __forceinline__ float bflo(unsigned int w) { return __uint_as_float(w << 16); }
__device__ __forceinline__ float bfhi(unsigned int w) { return __uint_as_float(w & 0xFFFF0000u); }

union FragU { uint4 u; s16x8 s; };

// Convert W_qk (16384 f32) and W_v (16384 f32) to bf16 in workspace.
__global__ void __launch_bounds__(256) prep_weights(const float* __restrict__ Wqk,
                                                    const float* __restrict__ Wv,
                                                    uint16_t* __restrict__ wsqk,
                                                    uint16_t* __restrict__ wsv) {
  int i = blockIdx.x * 256 + threadIdx.x;
  if (i < 16384) {
    wsqk[i] = (uint16_t)f2bf_u(Wqk[i]);
  } else if (i < 32768) {
    int j = i - 16384;
    wsv[j] = (uint16_t)f2bf_u(Wv[j]);
  }
}

// Wave-local structure: block (b, n0=4 n's), wave w owns n = n0+w end-to-end.
// X loaded pre-transposed from global (lane nn = k, 32 c-strided dwords, 64B
// coalesced per 16-lane group). P never touches LDS: acc -> Q/K MFMA frags via
// pack+shfl (quad-only movement). Single __syncthreads (sY/sS -> stage 3).
// LDS 18.8KB -> 8 blocks/CU; __launch_bounds__(256,8) caps VGPR at 64.
__global__ void __launch_bounds__(256, 8) attn_kernel(
    const float* __restrict__ X,          // (16,128,1024,16) f32
    const float* __restrict__ bqk,        // (128) f32
    const float* __restrict__ bv,         // (128) f32
    const unsigned int* __restrict__ wqk, // 128x128 bf16 as 8192 words
    const unsigned int* __restrict__ wv,  // 128x128 bf16 as 8192 words
    float* __restrict__ out)              // (16,1024,128) f32
{
  __shared__ unsigned int sXt[64 * 68];   // Xt[j=n*16+k][c-pair], row stride 68 words
  __shared__ unsigned int sY[4 * 68];     // y_n[c-pair] bf16
  __shared__ float sa[4][16];
  __shared__ float sS[4];

  const int t    = threadIdx.x;
  const int lane = t & 63;
  const int w    = t >> 6;      // wave 0..3 -> n = n0 + w
  const int nn   = lane & 15;
  const int quad = lane >> 4;

  const int blk = blockIdx.x;
  const int b   = blk >> 8;
  const int n0  = (blk & 255) << 2;
  const int n   = n0 + w;

  // ---- Stage L: global (pre-transposed lane roles) -> bf16 -> own sXt rows ----
  // lane (nn, quad): kk = nn; c = ks*32 + quad*8 + e. Each 16-lane nn-group
  // reads one full 64B line (c,n,k0..15); 4 quads = 4 lines per instruction.
  const int jrow = w * 16 + nn;
  {
    const float* Xb = X + (size_t)b * (128 * 1024 * 16) + (size_t)n * 16 + nn;
    #pragma unroll
    for (int ks = 0; ks < 4; ++ks) {
      float v[8];
      #pragma unroll
      for (int e = 0; e < 8; ++e) {
        const int c = ks * 32 + quad * 8 + e;
        v[e] = Xb[(size_t)c * 16384];
      }
      uint4 fw;
      fw.x = pack_bf2(v[0], v[1]);
      fw.y = pack_bf2(v[2], v[3]);
      fw.z = pack_bf2(v[4], v[5]);
      fw.w = pack_bf2(v[6], v[7]);
      *reinterpret_cast<uint4*>(&sXt[jrow * 68 + ks * 16 + quad * 4]) = fw;
    }
  }
  // Wave-private LDS handoff: same-wave DS ops are processed in order; no barrier.

  // ---- Stage 1: acc[ot] = Wqk(rows ot*16..) @ own Xt tile + bqk ----
  // acc: D[o = ot*16 + quad*4 + r][j-col = w*16 + nn]
  f32x4 acc[8];
  #pragma unroll
  for (int ot = 0; ot < 8; ++ot) {
    const float4 bq = *reinterpret_cast<const float4*>(bqk + ot * 16 + quad * 4);
    acc[ot][0] = bq.x; acc[ot][1] = bq.y; acc[ot][2] = bq.z; acc[ot][3] = bq.w;
  }
  #pragma unroll
  for (int ks = 0; ks < 4; ++ks) {
    FragU bfrag;
    bfrag.u = *reinterpret_cast<const uint4*>(&sXt[jrow * 68 + ks * 16 + quad * 4]);
    #pragma unroll
    for (int ot = 0; ot < 8; ++ot) {
      FragU af;   // all 4 waves read identical wqk addresses -> L1-hot
      af.u = *reinterpret_cast<const uint4*>(wqk + (ot * 16 + nn) * 64 + ks * 16 + quad * 4);
      acc[ot] = __builtin_amdgcn_mfma_f32_16x16x32_bf16(af.s, bfrag.s, acc[ot], 0, 0, 0);
    }
  }

  // ---- Stage 2: in-register repack acc -> Q/K frags; E = Q^T K; softmax ----
  // P[o][j] value for (o, j=w*16+nn') lives in lane nn=nn', quad_src=(o&15)>>2,
  // reg pair (o&3). Frag word e2 wants o-pair ks*32+quad*8+2e2 -> src lane
  // nn + 32*(quad&1) + 16*(e2>>1); reg array w01 (o&3 in {0,1}) / w23 ({2,3});
  // reg index ot = 2ks + (quad>>1) selected target-side after the shuffle.
  {
    unsigned int w01[8], w23[8];
    #pragma unroll
    for (int ot = 0; ot < 8; ++ot) {
      w01[ot] = pack_bf2(acc[ot][0], acc[ot][1]);
      w23[ot] = pack_bf2(acc[ot][2], acc[ot][3]);
    }
    const int src0 = nn + ((quad & 1) << 5);
    const int src1 = src0 + 16;
    const bool hi  = (quad >> 1) != 0;
    f32x4 e; e[0] = 0.f; e[1] = 0.f; e[2] = 0.f; e[3] = 0.f;
    #pragma unroll
    for (int ksq = 0; ksq < 2; ++ksq) {
      FragU qf, kf;
      {
        const int o0 = 2 * ksq, o1 = 2 * ksq + 1;           // Q: o < 64
        unsigned int a0 = __shfl(w01[o0], src0, 64), b0 = __shfl(w01[o1], src0, 64);
        unsigned int a1 = __shfl(w23[o0], src0, 64), b1 = __shfl(w23[o1], src0, 64);
        unsigned int a2 = __shfl(w01[o0], src1, 64), b2 = __shfl(w01[o1], src1, 64);
        unsigned int a3 = __shfl(w23[o0], src1, 64), b3 = __shfl(w23[o1], src1, 64);
        qf.u.x = hi ? b0 : a0; qf.u.y = hi ? b1 : a1;
        qf.u.z = hi ? b2 : a2; qf.u.w = hi ? b3 : a3;
      }
      {
        const int o0 = 4 + 2 * ksq, o1 = 5 + 2 * ksq;       // K: o >= 64
        unsigned int a0 = __shfl(w01[o0], src0, 64), b0 = __shfl(w01[o1], src0, 64);
        unsigned int a1 = __shfl(w23[o0], src0, 64), b1 = __shfl(w23[o1], src0, 64);
        unsigned int a2 = __shfl(w01[o0], src1, 64), b2 = __shfl(w01[o1], src1, 64);
        unsigned int a3 = __shfl(w23[o0], src1, 64), b3 = __shfl(w23[o1], src1, 64);
        kf.u.x = hi ? b0 : a0; kf.u.y = hi ? b1 : a1;
        kf.u.z = hi ? b2 : a2; kf.u.w = hi ? b3 : a3;
      }
      e = __builtin_amdgcn_mfma_f32_16x16x32_bf16(qf.s, kf.s, e, 0, 0, 0);
    }
    // softmax over k (cols = nn), rows q = quad*4 + r  (identical to proven code)
    float p[4], sm[4];
    #pragma unroll
    for (int rr = 0; rr < 4; ++rr) {
      float l = e[rr] * 0.125f;                        // /sqrt(64)
      float mx = l;
      mx = fmaxf(mx, __shfl_xor(mx, 1));
      mx = fmaxf(mx, __shfl_xor(mx, 2));
      mx = fmaxf(mx, __shfl_xor(mx, 4));
      mx = fmaxf(mx, __shfl_xor(mx, 8));
      float pe = __expf(l - mx);
      float ss = pe;
      ss += __shfl_xor(ss, 1);
      ss += __shfl_xor(ss, 2);
      ss += __shfl_xor(ss, 4);
      ss += __shfl_xor(ss, 8);
      p[rr] = pe; sm[rr] = ss;
    }
    if (nn == 0) {
      #pragma unroll
      for (int rr = 0; rr < 4; ++rr) sa[w][quad * 4 + rr] = p[rr] / sm[rr];
    }
  }

  // ---- Stage Y: y_n = X_n a_n -> sY row w (bf16); S_n (wave-local) ----
  {
    float a[16];
    float S = 0.f;
    #pragma unroll
    for (int k = 0; k < 16; ++k) { a[k] = sa[w][k]; S += a[k]; }
    float y0 = 0.f, y1 = 0.f;
    #pragma unroll
    for (int k = 0; k < 16; ++k) {
      const unsigned int xw = sXt[(w * 16 + k) * 68 + lane];   // stride-1: conflict-free
      y0 += a[k] * bflo(xw);
      y1 += a[k] * bfhi(xw);
    }
    sY[w * 68 + lane] = pack_bf2(y0, y1);
    if (lane == 0) sS[w] = S;
  }
  __syncthreads();   // the ONLY barrier: sY/sS produced per-wave, consumed cross-wave

  // ---- Stage 3: Out = Wv @ Y + bv * S ----
  {
    #pragma unroll
    for (int i = 0; i < 2; ++i) {
      const int ct = w * 2 + i;   // c-out tile, 8 tiles over 4 waves
      f32x4 z; z[0] = 0.f; z[1] = 0.f; z[2] = 0.f; z[3] = 0.f;
      #pragma unroll
      for (int ks = 0; ks < 4; ++ks) {
        FragU av, by;
        av.u = *reinterpret_cast<const uint4*>(wv + (ct * 16 + nn) * 64 + ks * 16 + quad * 4);
        uint4 tmp; tmp.x = 0u; tmp.y = 0u; tmp.z = 0u; tmp.w = 0u;
        if (nn < 4) tmp = *reinterpret_cast<const uint4*>(&sY[nn * 68 + ks * 16 + quad * 4]);
        by.u = tmp;
        z = __builtin_amdgcn_mfma_f32_16x16x32_bf16(av.s, by.s, z, 0, 0, 0);
      }
      if (nn < 4) {
        const float4 bvv = *reinterpret_cast<const float4*>(bv + ct * 16 + quad * 4);
        const float S = sS[nn];
        float4 o4;
        o4.x = z[0] + bvv.x * S;
        o4.y = z[1] + bvv.y * S;
        o4.z = z[2] + bvv.z * S;
        o4.w = z[3] + bvv.w * S;
        *reinterpret_cast<float4*>(out + (size_t)(b * 1024 + n0 + nn) * 128 + ct * 16 + quad * 4) = o4;
      }
    }
  }
}

extern "C" void kernel_launch(void* const* d_in, const int* in_sizes, int n_in,
                              void* d_out, int out_size, void* d_ws, size_t ws_size,
                              hipStream_t stream) {
  (void)in_sizes; (void)n_in; (void)out_size; (void)ws_size;
  const float* X   = (const float*)d_in[0];
  const float* Wqk = (const float*)d_in[1];
  const float* bqk = (const float*)d_in[2];
  const float* Wv  = (const float*)d_in[3];
  const float* bv  = (const float*)d_in[4];
  // d_in[5] = qk_dim (=64), compile-time constant here.

  uint16_t* wsqk = (uint16_t*)d_ws;           // 32 KB
  uint16_t* wsv  = wsqk + 16384;              // 32 KB

  prep_weights<<<128, 256, 0, stream>>>(Wqk, Wv, wsqk, wsv);
  attn_kernel<<<4096, 256, 0, stream>>>(X, bqk, bv,
                                        (const unsigned int*)wsqk,
                                        (const unsigned int*)wsv,
                                        (float*)d_out);
}

// Round 4
// 272.347 us; speedup vs baseline: 1.1067x; 1.1067x over previous
//
#include <hip/hip_runtime.h>
#include <stdint.h>

typedef __attribute__((ext_vector_type(4))) float f32x4;
typedef __attribute__((ext_vector_type(8))) short s16x8;

__device__ __forceinline__ unsigned int f2bf_u(float x) {
  union { float f; unsigned int u; } v; v.f = x;
  return (v.u + 0x7FFFu + ((v.u >> 16) & 1u)) >> 16;   // RNE
}
__device__ __forceinline__ unsigned int pack_bf2(float lo, float hi) {
  return f2bf_u(lo) | (f2bf_u(hi) << 16);
}
__device__ __forceinline__ float bflo(unsigned int w) { return __uint_as_float(w << 16); }
__device__ __forceinline__ float bfhi(unsigned int w) { return __uint_as_float(w & 0xFFFF0000u); }

union FragU { uint4 u; s16x8 s; };

// Convert W_qk (16384 f32) and W_v (16384 f32) to bf16 in workspace.
__global__ void __launch_bounds__(256) prep_weights(const float* __restrict__ Wqk,
                                                    const float* __restrict__ Wv,
                                                    uint16_t* __restrict__ wsqk,
                                                    uint16_t* __restrict__ wsv) {
  int i = blockIdx.x * 256 + threadIdx.x;
  if (i < 16384) {
    wsqk[i] = (uint16_t)f2bf_u(Wqk[i]);
  } else if (i < 32768) {
    int j = i - 16384;
    wsv[j] = (uint16_t)f2bf_u(Wv[j]);
  }
}

// Wave-local structure (R3, correctness-proven) with register-pressure fix:
// Stage 1+2 split into two halves h=0,1; half h computes only the 4 P-tiles
// feeding the ksq=h QK^T MFMA (ot in {2h,2h+1,4+2h,5+2h}), packs+shuffles,
// accumulates into e, releases regs. Peak acc live 32->16 VGPR.
// __launch_bounds__(256,6): VGPR cap ~84 (no spill; R3's (256,8) forced
// VGPR=32 -> 159MB scratch writes, the entire regression).
__global__ void __launch_bounds__(256, 6) attn_kernel(
    const float* __restrict__ X,          // (16,128,1024,16) f32
    const float* __restrict__ bqk,        // (128) f32
    const float* __restrict__ bv,         // (128) f32
    const unsigned int* __restrict__ wqk, // 128x128 bf16 as 8192 words
    const unsigned int* __restrict__ wv,  // 128x128 bf16 as 8192 words
    float* __restrict__ out)              // (16,1024,128) f32
{
  __shared__ unsigned int sXt[64 * 68];   // Xt[j=n*16+k][c-pair], row stride 68 words
  __shared__ unsigned int sY[4 * 68];     // y_n[c-pair] bf16
  __shared__ float sa[4][16];
  __shared__ float sS[4];

  const int t    = threadIdx.x;
  const int lane = t & 63;
  const int w    = t >> 6;      // wave 0..3 -> n = n0 + w
  const int nn   = lane & 15;
  const int quad = lane >> 4;

  const int blk = blockIdx.x;
  const int b   = blk >> 8;
  const int n0  = (blk & 255) << 2;
  const int n   = n0 + w;

  // ---- Stage L: global (pre-transposed lane roles) -> bf16 -> own sXt rows ----
  // lane (nn, quad): k = nn; c = ks*32 + quad*8 + e. Each 16-lane nn-group
  // reads one full 64B line; 4 quads = 4 lines per instruction (fully used).
  const int jrow = w * 16 + nn;
  {
    const float* Xb = X + (size_t)b * (128 * 1024 * 16) + (size_t)n * 16 + nn;
    #pragma unroll
    for (int ks = 0; ks < 4; ++ks) {
      float v[8];
      #pragma unroll
      for (int e = 0; e < 8; ++e) {
        const int c = ks * 32 + quad * 8 + e;
        v[e] = Xb[(size_t)c * 16384];
      }
      uint4 fw;
      fw.x = pack_bf2(v[0], v[1]);
      fw.y = pack_bf2(v[2], v[3]);
      fw.z = pack_bf2(v[4], v[5]);
      fw.w = pack_bf2(v[6], v[7]);
      *reinterpret_cast<uint4*>(&sXt[jrow * 68 + ks * 16 + quad * 4]) = fw;
    }
  }
  // Wave-private LDS handoff: same-wave DS ops complete in order; no barrier.

  // ---- Stage 1+2 fused, two halves: P-tiles -> pack -> shfl -> E mfma ----
  // acc: D[o = ot*16 + quad*4 + r][j-col = w*16 + nn]. Repack mapping verified
  // in R3: frag word e2 of lane (nn,quad) wants src lane nn+32*(quad&1)+16*(e2>>1),
  // hi-half selected by quad>>1, reg pair by o&3 (w01/w23), ot by 2h+(quad>>1)... 
  // (selection done target-side after shuffle, exactly as R3).
  f32x4 e; e[0] = 0.f; e[1] = 0.f; e[2] = 0.f; e[3] = 0.f;
  const int src0 = nn + ((quad & 1) << 5);
  const int src1 = src0 + 16;
  const bool hi  = (quad >> 1) != 0;

  #pragma unroll
  for (int h = 0; h < 2; ++h) {
    // ot set for this half: Q tiles 2h,2h+1 (o<64), K tiles 4+2h,5+2h (o>=64)
    f32x4 acc[4];
    #pragma unroll
    for (int i = 0; i < 4; ++i) {
      const int ot = (i < 2) ? (2 * h + i) : (4 + 2 * h + (i - 2));
      const float4 bq = *reinterpret_cast<const float4*>(bqk + ot * 16 + quad * 4);
      acc[i][0] = bq.x; acc[i][1] = bq.y; acc[i][2] = bq.z; acc[i][3] = bq.w;
    }
    #pragma unroll
    for (int ks = 0; ks < 4; ++ks) {
      FragU bfrag;
      bfrag.u = *reinterpret_cast<const uint4*>(&sXt[jrow * 68 + ks * 16 + quad * 4]);
      #pragma unroll
      for (int i = 0; i < 4; ++i) {
        const int ot = (i < 2) ? (2 * h + i) : (4 + 2 * h + (i - 2));
        FragU af;   // all 4 waves read identical wqk addresses -> L1-hot
        af.u = *reinterpret_cast<const uint4*>(wqk + (ot * 16 + nn) * 64 + ks * 16 + quad * 4);
        acc[i] = __builtin_amdgcn_mfma_f32_16x16x32_bf16(af.s, bfrag.s, acc[i], 0, 0, 0);
      }
    }
    unsigned int w01[4], w23[4];
    #pragma unroll
    for (int i = 0; i < 4; ++i) {
      w01[i] = pack_bf2(acc[i][0], acc[i][1]);
      w23[i] = pack_bf2(acc[i][2], acc[i][3]);
    }
    FragU qf, kf;
    {
      unsigned int a0 = __shfl(w01[0], src0, 64), b0 = __shfl(w01[1], src0, 64);
      unsigned int a1 = __shfl(w23[0], src0, 64), b1 = __shfl(w23[1], src0, 64);
      unsigned int a2 = __shfl(w01[0], src1, 64), b2 = __shfl(w01[1], src1, 64);
      unsigned int a3 = __shfl(w23[0], src1, 64), b3 = __shfl(w23[1], src1, 64);
      qf.u.x = hi ? b0 : a0; qf.u.y = hi ? b1 : a1;
      qf.u.z = hi ? b2 : a2; qf.u.w = hi ? b3 : a3;
    }
    {
      unsigned int a0 = __shfl(w01[2], src0, 64), b0 = __shfl(w01[3], src0, 64);
      unsigned int a1 = __shfl(w23[2], src0, 64), b1 = __shfl(w23[3], src0, 64);
      unsigned int a2 = __shfl(w01[2], src1, 64), b2 = __shfl(w01[3], src1, 64);
      unsigned int a3 = __shfl(w23[2], src1, 64), b3 = __shfl(w23[3], src1, 64);
      kf.u.x = hi ? b0 : a0; kf.u.y = hi ? b1 : a1;
      kf.u.z = hi ? b2 : a2; kf.u.w = hi ? b3 : a3;
    }
    e = __builtin_amdgcn_mfma_f32_16x16x32_bf16(qf.s, kf.s, e, 0, 0, 0);
  }

  // ---- softmax over k (cols = nn), rows q = quad*4 + rr ----
  {
    float p[4], sm[4];
    #pragma unroll
    for (int rr = 0; rr < 4; ++rr) {
      float l = e[rr] * 0.125f;                        // /sqrt(64)
      float mx = l;
      mx = fmaxf(mx, __shfl_xor(mx, 1));
      mx = fmaxf(mx, __shfl_xor(mx, 2));
      mx = fmaxf(mx, __shfl_xor(mx, 4));
      mx = fmaxf(mx, __shfl_xor(mx, 8));
      float pe = __expf(l - mx);
      float ss = pe;
      ss += __shfl_xor(ss, 1);
      ss += __shfl_xor(ss, 2);
      ss += __shfl_xor(ss, 4);
      ss += __shfl_xor(ss, 8);
      p[rr] = pe; sm[rr] = ss;
    }
    if (nn == 0) {
      #pragma unroll
      for (int rr = 0; rr < 4; ++rr) sa[w][quad * 4 + rr] = p[rr] / sm[rr];
    }
  }

  // ---- Stage Y: y_n = X_n a_n -> sY row w (bf16); S_n (wave-local) ----
  {
    float a[16];
    float S = 0.f;
    #pragma unroll
    for (int k = 0; k < 16; ++k) { a[k] = sa[w][k]; S += a[k]; }
    float y0 = 0.f, y1 = 0.f;
    #pragma unroll
    for (int k = 0; k < 16; ++k) {
      const unsigned int xw = sXt[(w * 16 + k) * 68 + lane];   // stride-1: conflict-free
      y0 += a[k] * bflo(xw);
      y1 += a[k] * bfhi(xw);
    }
    sY[w * 68 + lane] = pack_bf2(y0, y1);
    if (lane == 0) sS[w] = S;
  }
  __syncthreads();   // the ONLY barrier: sY/sS produced per-wave, consumed cross-wave

  // ---- Stage 3: Out = Wv @ Y + bv * S ----
  {
    #pragma unroll
    for (int i = 0; i < 2; ++i) {
      const int ct = w * 2 + i;   // c-out tile, 8 tiles over 4 waves
      f32x4 z; z[0] = 0.f; z[1] = 0.f; z[2] = 0.f; z[3] = 0.f;
      #pragma unroll
      for (int ks = 0; ks < 4; ++ks) {
        FragU av, by;
        av.u = *reinterpret_cast<const uint4*>(wv + (ct * 16 + nn) * 64 + ks * 16 + quad * 4);
        uint4 tmp; tmp.x = 0u; tmp.y = 0u; tmp.z = 0u; tmp.w = 0u;
        if (nn < 4) tmp = *reinterpret_cast<const uint4*>(&sY[nn * 68 + ks * 16 + quad * 4]);
        by.u = tmp;
        z = __builtin_amdgcn_mfma_f32_16x16x32_bf16(av.s, by.s, z, 0, 0, 0);
      }
      if (nn < 4) {
        const float4 bvv = *reinterpret_cast<const float4*>(bv + ct * 16 + quad * 4);
        const float S = sS[nn];
        float4 o4;
        o4.x = z[0] + bvv.x * S;
        o4.y = z[1] + bvv.y * S;
        o4.z = z[2] + bvv.z * S;
        o4.w = z[3] + bvv.w * S;
        *reinterpret_cast<float4*>(out + (size_t)(b * 1024 + n0 + nn) * 128 + ct * 16 + quad * 4) = o4;
      }
    }
  }
}

extern "C" void kernel_launch(void* const* d_in, const int* in_sizes, int n_in,
                              void* d_out, int out_size, void* d_ws, size_t ws_size,
                              hipStream_t stream) {
  (void)in_sizes; (void)n_in; (void)out_size; (void)ws_size;
  const float* X   = (const float*)d_in[0];
  const float* Wqk = (const float*)d_in[1];
  const float* bqk = (const float*)d_in[2];
  const float* Wv  = (const float*)d_in[3];
  const float* bv  = (const float*)d_in[4];
  // d_in[5] = qk_dim (=64), compile-time constant here.

  uint16_t* wsqk = (uint16_t*)d_ws;           // 32 KB
  uint16_t* wsv  = wsqk + 16384;              // 32 KB

  prep_weights<<<128, 256, 0, stream>>>(Wqk, Wv, wsqk, wsv);
  attn_kernel<<<4096, 256, 0, stream>>>(X, bqk, bv,
                                        (const unsigned int*)wsqk,
                                        (const unsigned int*)wsv,
                                        (float*)d_out);
}

// Round 5
// 259.160 us; speedup vs baseline: 1.1631x; 1.0509x over previous
//
#include <hip/hip_runtime.h>
#include <stdint.h>

typedef __attribute__((ext_vector_type(4))) float f32x4;
typedef __attribute__((ext_vector_type(8))) short s16x8;

__device__ __forceinline__ unsigned int f2bf_u(float x) {
  union { float f; unsigned int u; } v; v.f = x;
  return (v.u + 0x7FFFu + ((v.u >> 16) & 1u)) >> 16;   // RNE
}
__device__ __forceinline__ unsigned int pack_bf2(float lo, float hi) {
  return f2bf_u(lo) | (f2bf_u(hi) << 16);
}
__device__ __forceinline__ float bflo(unsigned int w) { return __uint_as_float(w << 16); }
__device__ __forceinline__ float bfhi(unsigned int w) { return __uint_as_float(w & 0xFFFF0000u); }

union FragU { uint4 u; s16x8 s; };

// Convert W_qk (16384 f32) and W_v (16384 f32) to bf16 in workspace.
__global__ void __launch_bounds__(256) prep_weights(const float* __restrict__ Wqk,
                                                    const float* __restrict__ Wv,
                                                    uint16_t* __restrict__ wsqk,
                                                    uint16_t* __restrict__ wsv) {
  int i = blockIdx.x * 256 + threadIdx.x;
  if (i < 16384) {
    wsqk[i] = (uint16_t)f2bf_u(Wqk[i]);
  } else if (i < 32768) {
    int j = i - 16384;
    wsv[j] = (uint16_t)f2bf_u(Wv[j]);
  }
}

// R4 wave-local skeleton (proven) + fixed staging:
// Stage A loads X with R2-style coalesced float4 (8 loads/thread — R4's 32
// scalar strided loads were ~55us of pure VMEM issue), then a 4x4 cross-quad
// in-register transpose (2 rounds of shfl_xor 32/16) yields per-lane c-columns,
// packed bf16 and written as one b64 per iter into transposed sXt.
// Row stride 66 words: stage-1 b128 reads land at the 8-way b128 minimum
// (conflict-free); stage-Y reads are stride-1.
__global__ void __launch_bounds__(256, 6) attn_kernel(
    const float* __restrict__ X,          // (16,128,1024,16) f32
    const float* __restrict__ bqk,        // (128) f32
    const float* __restrict__ bv,         // (128) f32
    const unsigned int* __restrict__ wqk, // 128x128 bf16 as 8192 words
    const unsigned int* __restrict__ wv,  // 128x128 bf16 as 8192 words
    float* __restrict__ out)              // (16,1024,128) f32
{
  __shared__ unsigned int sXt[64 * 66];   // Xt[j=n*16+k][c-pair], row stride 66 words
  __shared__ unsigned int sY[4 * 68];     // y_n[c-pair] bf16
  __shared__ float sa[4][16];
  __shared__ float sS[4];

  const int t    = threadIdx.x;
  const int lane = t & 63;
  const int w    = t >> 6;      // wave 0..3 -> n = n0 + w
  const int nn   = lane & 15;
  const int quad = lane >> 4;

  const int blk = blockIdx.x;
  const int b   = blk >> 8;
  const int n0  = (blk & 255) << 2;

  // ---- Stage A: coalesced float4 + in-register 4x4 quad transpose -> sXt ----
  // Quad-group {lane, lane^16, lane^32, lane^48} shares j4=nn, it, w; holds
  // rows c = cbase+q. After transpose lane q holds column j = 4*j4+q of the
  // 4 c-rows; packs (c0,c1),(c2,c3) and writes b64 at sXt[j][cbase/2].
  {
    const int j4 = nn;
    const int q  = quad;
    const float* Xg = X + (size_t)b * (128 * 1024 * 16) + (size_t)n0 * 16;
    #pragma unroll
    for (int it = 0; it < 8; ++it) {
      const int cbase = it * 16 + w * 4;      // multiple of 4
      const int c = cbase + q;
      float4 V = *reinterpret_cast<const float4*>(Xg + (size_t)c * 16384 + j4 * 4);
      // Round 1: xor 32 (block swap across Q = q>>1)
      {
        const bool Q0 = (q >> 1) == 0;
        float a  = Q0 ? V.z : V.x;
        float bb = Q0 ? V.w : V.y;
        a  = __shfl_xor(a, 32);
        bb = __shfl_xor(bb, 32);
        if (Q0) { V.z = a; V.w = bb; } else { V.x = a; V.y = bb; }
      }
      // Round 2: xor 16 (inner swap across q&1)
      {
        const bool q0 = (q & 1) == 0;
        float a  = q0 ? V.y : V.x;
        float bb = q0 ? V.w : V.z;
        a  = __shfl_xor(a, 16);
        bb = __shfl_xor(bb, 16);
        if (q0) { V.y = a; V.w = bb; } else { V.x = a; V.z = bb; }
      }
      // V = {X[cbase+0][j], X[cbase+1][j], X[cbase+2][j], X[cbase+3][j]}, j = 4*j4+q
      const int j = 4 * j4 + q;
      uint2 pk;
      pk.x = pack_bf2(V.x, V.y);
      pk.y = pack_bf2(V.z, V.w);
      *reinterpret_cast<uint2*>(&sXt[j * 66 + (cbase >> 1)]) = pk;
    }
  }
  __syncthreads();   // staging is cross-wave (cp coverage spans w)

  const int jrow = w * 16 + nn;

  // ---- Stage 1+2 fused, two halves: P-tiles -> pack -> shfl -> E mfma ----
  // (identical to R4's proven code; only sXt stride 68 -> 66)
  f32x4 e; e[0] = 0.f; e[1] = 0.f; e[2] = 0.f; e[3] = 0.f;
  const int src0 = nn + ((quad & 1) << 5);
  const int src1 = src0 + 16;
  const bool hi  = (quad >> 1) != 0;

  #pragma unroll
  for (int h = 0; h < 2; ++h) {
    f32x4 acc[4];
    #pragma unroll
    for (int i = 0; i < 4; ++i) {
      const int ot = (i < 2) ? (2 * h + i) : (4 + 2 * h + (i - 2));
      const float4 bq = *reinterpret_cast<const float4*>(bqk + ot * 16 + quad * 4);
      acc[i][0] = bq.x; acc[i][1] = bq.y; acc[i][2] = bq.z; acc[i][3] = bq.w;
    }
    #pragma unroll
    for (int ks = 0; ks < 4; ++ks) {
      FragU bfrag;
      bfrag.u = *reinterpret_cast<const uint4*>(&sXt[jrow * 66 + ks * 16 + quad * 4]);
      #pragma unroll
      for (int i = 0; i < 4; ++i) {
        const int ot = (i < 2) ? (2 * h + i) : (4 + 2 * h + (i - 2));
        FragU af;   // all 4 waves read identical wqk addresses -> L1-hot
        af.u = *reinterpret_cast<const uint4*>(wqk + (ot * 16 + nn) * 64 + ks * 16 + quad * 4);
        acc[i] = __builtin_amdgcn_mfma_f32_16x16x32_bf16(af.s, bfrag.s, acc[i], 0, 0, 0);
      }
    }
    unsigned int w01[4], w23[4];
    #pragma unroll
    for (int i = 0; i < 4; ++i) {
      w01[i] = pack_bf2(acc[i][0], acc[i][1]);
      w23[i] = pack_bf2(acc[i][2], acc[i][3]);
    }
    FragU qf, kf;
    {
      unsigned int a0 = __shfl(w01[0], src0, 64), b0 = __shfl(w01[1], src0, 64);
      unsigned int a1 = __shfl(w23[0], src0, 64), b1 = __shfl(w23[1], src0, 64);
      unsigned int a2 = __shfl(w01[0], src1, 64), b2 = __shfl(w01[1], src1, 64);
      unsigned int a3 = __shfl(w23[0], src1, 64), b3 = __shfl(w23[1], src1, 64);
      qf.u.x = hi ? b0 : a0; qf.u.y = hi ? b1 : a1;
      qf.u.z = hi ? b2 : a2; qf.u.w = hi ? b3 : a3;
    }
    {
      unsigned int a0 = __shfl(w01[2], src0, 64), b0 = __shfl(w01[3], src0, 64);
      unsigned int a1 = __shfl(w23[2], src0, 64), b1 = __shfl(w23[3], src0, 64);
      unsigned int a2 = __shfl(w01[2], src1, 64), b2 = __shfl(w01[3], src1, 64);
      unsigned int a3 = __shfl(w23[2], src1, 64), b3 = __shfl(w23[3], src1, 64);
      kf.u.x = hi ? b0 : a0; kf.u.y = hi ? b1 : a1;
      kf.u.z = hi ? b2 : a2; kf.u.w = hi ? b3 : a3;
    }
    e = __builtin_amdgcn_mfma_f32_16x16x32_bf16(qf.s, kf.s, e, 0, 0, 0);
  }

  // ---- softmax over k (cols = nn), rows q = quad*4 + rr ----
  {
    float p[4], sm[4];
    #pragma unroll
    for (int rr = 0; rr < 4; ++rr) {
      float l = e[rr] * 0.125f;                        // /sqrt(64)
      float mx = l;
      mx = fmaxf(mx, __shfl_xor(mx, 1));
      mx = fmaxf(mx, __shfl_xor(mx, 2));
      mx = fmaxf(mx, __shfl_xor(mx, 4));
      mx = fmaxf(mx, __shfl_xor(mx, 8));
      float pe = __expf(l - mx);
      float ss = pe;
      ss += __shfl_xor(ss, 1);
      ss += __shfl_xor(ss, 2);
      ss += __shfl_xor(ss, 4);
      ss += __shfl_xor(ss, 8);
      p[rr] = pe; sm[rr] = ss;
    }
    if (nn == 0) {
      #pragma unroll
      for (int rr = 0; rr < 4; ++rr) sa[w][quad * 4 + rr] = p[rr] / sm[rr];
    }
  }

  // ---- Stage Y: y_n = X_n a_n -> sY row w (bf16); S_n (wave-local) ----
  {
    float a[16];
    float S = 0.f;
    #pragma unroll
    for (int k = 0; k < 16; ++k) { a[k] = sa[w][k]; S += a[k]; }
    float y0 = 0.f, y1 = 0.f;
    #pragma unroll
    for (int k = 0; k < 16; ++k) {
      const unsigned int xw = sXt[(w * 16 + k) * 66 + lane];   // stride-1: conflict-free
      y0 += a[k] * bflo(xw);
      y1 += a[k] * bfhi(xw);
    }
    sY[w * 68 + lane] = pack_bf2(y0, y1);
    if (lane == 0) sS[w] = S;
  }
  __syncthreads();   // sY/sS produced per-wave, consumed cross-wave

  // ---- Stage 3: Out = Wv @ Y + bv * S ----
  {
    #pragma unroll
    for (int i = 0; i < 2; ++i) {
      const int ct = w * 2 + i;   // c-out tile, 8 tiles over 4 waves
      f32x4 z; z[0] = 0.f; z[1] = 0.f; z[2] = 0.f; z[3] = 0.f;
      #pragma unroll
      for (int ks = 0; ks < 4; ++ks) {
        FragU av, by;
        av.u = *reinterpret_cast<const uint4*>(wv + (ct * 16 + nn) * 64 + ks * 16 + quad * 4);
        uint4 tmp; tmp.x = 0u; tmp.y = 0u; tmp.z = 0u; tmp.w = 0u;
        if (nn < 4) tmp = *reinterpret_cast<const uint4*>(&sY[nn * 68 + ks * 16 + quad * 4]);
        by.u = tmp;
        z = __builtin_amdgcn_mfma_f32_16x16x32_bf16(av.s, by.s, z, 0, 0, 0);
      }
      if (nn < 4) {
        const float4 bvv = *reinterpret_cast<const float4*>(bv + ct * 16 + quad * 4);
        const float S = sS[nn];
        float4 o4;
        o4.x = z[0] + bvv.x * S;
        o4.y = z[1] + bvv.y * S;
        o4.z = z[2] + bvv.z * S;
        o4.w = z[3] + bvv.w * S;
        *reinterpret_cast<float4*>(out + (size_t)(b * 1024 + n0 + nn) * 128 + ct * 16 + quad * 4) = o4;
      }
    }
  }
}

extern "C" void kernel_launch(void* const* d_in, const int* in_sizes, int n_in,
                              void* d_out, int out_size, void* d_ws, size_t ws_size,
                              hipStream_t stream) {
  (void)in_sizes; (void)n_in; (void)out_size; (void)ws_size;
  const float* X   = (const float*)d_in[0];
  const float* Wqk = (const float*)d_in[1];
  const float* bqk = (const float*)d_in[2];
  const float* Wv  = (const float*)d_in[3];
  const float* bv  = (const float*)d_in[4];
  // d_in[5] = qk_dim (=64), compile-time constant here.

  uint16_t* wsqk = (uint16_t*)d_ws;           // 32 KB
  uint16_t* wsv  = wsqk + 16384;              // 32 KB

  prep_weights<<<128, 256, 0, stream>>>(Wqk, Wv, wsqk, wsv);
  attn_kernel<<<4096, 256, 0, stream>>>(X, bqk, bv,
                                        (const unsigned int*)wsqk,
                                        (const unsigned int*)wsv,
                                        (float*)d_out);
}

// Round 6
// 218.849 us; speedup vs baseline: 1.3773x; 1.1842x over previous
//
#include <hip/hip_runtime.h>
#include <stdint.h>

typedef __attribute__((ext_vector_type(4))) float f32x4;
typedef __attribute__((ext_vector_type(8))) short s16x8;

__device__ __forceinline__ unsigned int f2bf_u(float x) {
  union { float f; unsigned int u; } v; v.f = x;
  return (v.u + 0x7FFFu + ((v.u >> 16) & 1u)) >> 16;   // RNE
}
__device__ __forceinline__ unsigned int pack_bf2(float lo, float hi) {
  return f2bf_u(lo) | (f2bf_u(hi) << 16);
}
__device__ __forceinline__ float bflo(unsigned int w) { return __uint_as_float(w << 16); }
__device__ __forceinline__ float bfhi(unsigned int w) { return __uint_as_float(w & 0xFFFF0000u); }

union FragU { uint4 u; s16x8 s; };

// Convert W_qk (16384 f32) and W_v (16384 f32) to bf16 in workspace.
__global__ void __launch_bounds__(256) prep_weights(const float* __restrict__ Wqk,
                                                    const float* __restrict__ Wv,
                                                    uint16_t* __restrict__ wsqk,
                                                    uint16_t* __restrict__ wsv) {
  int i = blockIdx.x * 256 + threadIdx.x;
  if (i < 16384) {
    wsqk[i] = (uint16_t)f2bf_u(Wqk[i]);
  } else if (i < 32768) {
    int j = i - 16384;
    wsv[j] = (uint16_t)f2bf_u(Wv[j]);
  }
}

// R0's cross-wave dataflow (best measured L) at 6 blocks/CU:
//  - Stage A: R5's in-register 4x4 quad transpose (coalesced float4) -> sXt
//    directly; kills R0's 17KB natural-staging buffer + a barrier.
//  - Stage 1 split into two o-halves (h: Q[32h..32h+31], K[64+32h..]);
//    Pt buffer halves to 64x34 words (8.7KB). Stage 2 consumes each half
//    with one MFMA (same slice semantics as R0's ks=h read), e accumulated
//    across halves in registers.
//  - LDS 26.9KB -> 6 blocks/CU; 5 barriers; launch_bounds(256,6) (cap 85).
__global__ void __launch_bounds__(256, 6) attn_kernel(
    const float* __restrict__ X,          // (16,128,1024,16) f32
    const float* __restrict__ bqk,        // (128) f32
    const float* __restrict__ bv,         // (128) f32
    const unsigned int* __restrict__ wqk, // 128x128 bf16 as 8192 words
    const unsigned int* __restrict__ wv,  // 128x128 bf16 as 8192 words
    float* __restrict__ out)              // (16,1024,128) f32
{
  __shared__ unsigned int sXt[64 * 66];   // Xt[j=n*16+k][c-pair], stride 66 words
  __shared__ unsigned int sPt[64 * 34];   // P^T half: [j][o-pair 0..31], stride 34
  __shared__ unsigned int sY[4 * 68];     // y_n[c-pair] bf16
  __shared__ float sa[4][16];
  __shared__ float sS[4];

  const int t    = threadIdx.x;
  const int lane = t & 63;
  const int w    = t >> 6;      // wave 0..3
  const int nn   = lane & 15;
  const int quad = lane >> 4;

  const int blk = blockIdx.x;
  const int b   = blk >> 8;
  const int n0  = (blk & 255) << 2;

  // ---- Stage A: coalesced float4 + in-register 4x4 quad transpose -> sXt ----
  // (verbatim from R5, correctness-proven)
  {
    const int j4 = nn;
    const int q  = quad;
    const float* Xg = X + (size_t)b * (128 * 1024 * 16) + (size_t)n0 * 16;
    #pragma unroll
    for (int it = 0; it < 8; ++it) {
      const int cbase = it * 16 + w * 4;      // multiple of 4
      const int c = cbase + q;
      float4 V = *reinterpret_cast<const float4*>(Xg + (size_t)c * 16384 + j4 * 4);
      {
        const bool Q0 = (q >> 1) == 0;
        float a  = Q0 ? V.z : V.x;
        float bb = Q0 ? V.w : V.y;
        a  = __shfl_xor(a, 32);
        bb = __shfl_xor(bb, 32);
        if (Q0) { V.z = a; V.w = bb; } else { V.x = a; V.y = bb; }
      }
      {
        const bool q0 = (q & 1) == 0;
        float a  = q0 ? V.y : V.x;
        float bb = q0 ? V.w : V.z;
        a  = __shfl_xor(a, 16);
        bb = __shfl_xor(bb, 16);
        if (q0) { V.y = a; V.w = bb; } else { V.x = a; V.z = bb; }
      }
      const int j = 4 * j4 + q;
      uint2 pk;
      pk.x = pack_bf2(V.x, V.y);
      pk.y = pack_bf2(V.z, V.w);
      *reinterpret_cast<uint2*>(&sXt[j * 66 + (cbase >> 1)]) = pk;
    }
  }
  __syncthreads();

  f32x4 e; e[0] = 0.f; e[1] = 0.f; e[2] = 0.f; e[3] = 0.f;

  #pragma unroll
  for (int h = 0; h < 2; ++h) {
    // ---- Stage 1 half h: 64 o's (Q 32h.., K 64+32h..) split over 4 waves ----
    // wave 0,1 -> Q tiles; wave 2,3 -> K tiles. acc: D[o=O+quad*4+r][j=tt*16+nn]
    const int O       = (w < 2) ? (32 * h + 16 * w) : (64 + 32 * h + 16 * (w - 2));
    const int colbase = (w < 2) ? (8 * w)           : (16 + 8 * (w - 2));
    f32x4 acc[4];
    {
      const float4 bq = *reinterpret_cast<const float4*>(bqk + O + quad * 4);
      #pragma unroll
      for (int tt = 0; tt < 4; ++tt) {
        acc[tt][0] = bq.x; acc[tt][1] = bq.y; acc[tt][2] = bq.z; acc[tt][3] = bq.w;
      }
    }
    #pragma unroll
    for (int ks = 0; ks < 4; ++ks) {
      FragU af, bf[4];
      af.u = *reinterpret_cast<const uint4*>(wqk + (O + nn) * 64 + ks * 16 + quad * 4);
      #pragma unroll
      for (int tt = 0; tt < 4; ++tt)
        bf[tt].u = *reinterpret_cast<const uint4*>(&sXt[(tt * 16 + nn) * 66 + ks * 16 + quad * 4]);
      #pragma unroll
      for (int tt = 0; tt < 4; ++tt)
        acc[tt] = __builtin_amdgcn_mfma_f32_16x16x32_bf16(af.s, bf[tt].s, acc[tt], 0, 0, 0);
    }
    // Epilogue: Pt[j][colbase + quad*2 + {0,1}] (pair parity trick from R0)
    #pragma unroll
    for (int tt = 0; tt < 4; ++tt) {
      const int j = tt * 16 + nn;
      const unsigned int pw0 = pack_bf2(acc[tt][0], acc[tt][1]);
      const unsigned int pw1 = pack_bf2(acc[tt][2], acc[tt][3]);
      #pragma unroll
      for (int s = 0; s < 2; ++s) {
        const int rp = (nn + s) & 1;
        sPt[j * 34 + colbase + quad * 2 + rp] = rp ? pw1 : pw0;
      }
    }
    __syncthreads();   // Pt half complete -> all waves may read

    // ---- Stage 2 half h: E += Q_h^T K_h (wave w -> n=w) ----
    // Q at pair-cols 0..15, K at 16..31 (exactly R0's ks=h slice layout).
    {
      const int row = (w * 16 + nn) * 34;
      FragU qf, kf;
      const uint2 qlo = *reinterpret_cast<const uint2*>(&sPt[row + quad * 4]);
      const uint2 qhi = *reinterpret_cast<const uint2*>(&sPt[row + quad * 4 + 2]);
      const uint2 klo = *reinterpret_cast<const uint2*>(&sPt[row + 16 + quad * 4]);
      const uint2 khi = *reinterpret_cast<const uint2*>(&sPt[row + 16 + quad * 4 + 2]);
      qf.u.x = qlo.x; qf.u.y = qlo.y; qf.u.z = qhi.x; qf.u.w = qhi.y;
      kf.u.x = klo.x; kf.u.y = klo.y; kf.u.z = khi.x; kf.u.w = khi.y;
      e = __builtin_amdgcn_mfma_f32_16x16x32_bf16(qf.s, kf.s, e, 0, 0, 0);
    }
    if (h == 0) __syncthreads();   // protect Pt from half-1 overwrite
  }

  // ---- softmax over k (cols = nn), rows q = quad*4 + rr (R0 verbatim) ----
  {
    float p[4], sm[4];
    #pragma unroll
    for (int rr = 0; rr < 4; ++rr) {
      float l = e[rr] * 0.125f;                        // /sqrt(64)
      float mx = l;
      mx = fmaxf(mx, __shfl_xor(mx, 1));
      mx = fmaxf(mx, __shfl_xor(mx, 2));
      mx = fmaxf(mx, __shfl_xor(mx, 4));
      mx = fmaxf(mx, __shfl_xor(mx, 8));
      float pe = __expf(l - mx);
      float ss = pe;
      ss += __shfl_xor(ss, 1);
      ss += __shfl_xor(ss, 2);
      ss += __shfl_xor(ss, 4);
      ss += __shfl_xor(ss, 8);
      p[rr] = pe; sm[rr] = ss;
    }
    if (nn == 0) {
      #pragma unroll
      for (int rr = 0; rr < 4; ++rr) sa[w][quad * 4 + rr] = p[rr] / sm[rr];
    }
  }

  // ---- Stage Y: y_n = X_n a_n -> sY row w (bf16); S_n (wave-local) ----
  // sY is its own buffer: no hazard with other waves' in-flight Pt reads.
  {
    float a[16];
    float S = 0.f;
    #pragma unroll
    for (int k = 0; k < 16; ++k) { a[k] = sa[w][k]; S += a[k]; }
    float y0 = 0.f, y1 = 0.f;
    #pragma unroll
    for (int k = 0; k < 16; ++k) {
      const unsigned int xw = sXt[(w * 16 + k) * 66 + lane];   // stride-1
      y0 += a[k] * bflo(xw);
      y1 += a[k] * bfhi(xw);
    }
    sY[w * 68 + lane] = pack_bf2(y0, y1);
    if (lane == 0) sS[w] = S;
  }
  __syncthreads();   // sY/sS cross-wave -> stage 3

  // ---- Stage 3: Out = Wv @ Y + bv * S (proven verbatim) ----
  {
    #pragma unroll
    for (int i = 0; i < 2; ++i) {
      const int ct = w * 2 + i;   // c-out tile, 8 tiles over 4 waves
      f32x4 z; z[0] = 0.f; z[1] = 0.f; z[2] = 0.f; z[3] = 0.f;
      #pragma unroll
      for (int ks = 0; ks < 4; ++ks) {
        FragU av, by;
        av.u = *reinterpret_cast<const uint4*>(wv + (ct * 16 + nn) * 64 + ks * 16 + quad * 4);
        uint4 tmp; tmp.x = 0u; tmp.y = 0u; tmp.z = 0u; tmp.w = 0u;
        if (nn < 4) tmp = *reinterpret_cast<const uint4*>(&sY[nn * 68 + ks * 16 + quad * 4]);
        by.u = tmp;
        z = __builtin_amdgcn_mfma_f32_16x16x32_bf16(av.s, by.s, z, 0, 0, 0);
      }
      if (nn < 4) {
        const float4 bvv = *reinterpret_cast<const float4*>(bv + ct * 16 + quad * 4);
        const float S = sS[nn];
        float4 o4;
        o4.x = z[0] + bvv.x * S;
        o4.y = z[1] + bvv.y * S;
        o4.z = z[2] + bvv.z * S;
        o4.w = z[3] + bvv.w * S;
        *reinterpret_cast<float4*>(out + (size_t)(b * 1024 + n0 + nn) * 128 + ct * 16 + quad * 4) = o4;
      }
    }
  }
}

extern "C" void kernel_launch(void* const* d_in, const int* in_sizes, int n_in,
                              void* d_out, int out_size, void* d_ws, size_t ws_size,
                              hipStream_t stream) {
  (void)in_sizes; (void)n_in; (void)out_size; (void)ws_size;
  const float* X   = (const float*)d_in[0];
  const float* Wqk = (const float*)d_in[1];
  const float* bqk = (const float*)d_in[2];
  const float* Wv  = (const float*)d_in[3];
  const float* bv  = (const float*)d_in[4];
  // d_in[5] = qk_dim (=64), compile-time constant here.

  uint16_t* wsqk = (uint16_t*)d_ws;           // 32 KB
  uint16_t* wsv  = wsqk + 16384;              // 32 KB

  prep_weights<<<128, 256, 0, stream>>>(Wqk, Wv, wsqk, wsv);
  attn_kernel<<<4096, 256, 0, stream>>>(X, bqk, bv,
                                        (const unsigned int*)wsqk,
                                        (const unsigned int*)wsv,
                                        (float*)d_out);
}